// Round 1
// baseline (20368.510 us; speedup 1.0000x reference)
//
#include <hip/hip_runtime.h>
#include <hip/hip_bf16.h>
#include <hip/hip_cooperative_groups.h>

namespace cg = cooperative_groups;

#define SEQ    256
#define BATCH  64
#define HID    1024
#define G4     4096
#define NWG    256
#define LDK    1032   // padded LDS row stride (bf16 elems): 1024+8 -> 2064B rows, 2-way bank alias only

typedef __bf16 bf16x8 __attribute__((ext_vector_type(8)));
typedef float  f32x4  __attribute__((ext_vector_type(4)));
typedef unsigned short u16;

__device__ __forceinline__ u16 f2bf(float f) {
    unsigned int u = __float_as_uint(f);
    unsigned int r = (u + 0x7fffu + ((u >> 16) & 1u)) >> 16;  // RNE
    return (u16)r;
}

__device__ __forceinline__ float sigmoid_f(float x) {
    x = fminf(fmaxf(x, -30.f), 30.f);
    return 1.f / (1.f + __expf(-x));
}
__device__ __forceinline__ float tanh_f(float x) {
    x = fminf(fmaxf(x, -15.f), 15.f);
    float e2 = __expf(2.f * x);
    return (e2 - 1.f) / (e2 + 1.f);
}

// ---------------- fp32 -> bf16 conversion (x) ----------------
__global__ void cvt_f32_bf16(const float* __restrict__ in, u16* __restrict__ out, int n4) {
    int idx = blockIdx.x * blockDim.x + threadIdx.x;
    int stride = gridDim.x * blockDim.x;
    const float4* in4 = (const float4*)in;
    ushort4* out4 = (ushort4*)out;
    for (int i = idx; i < n4; i += stride) {
        float4 v = in4[i];
        ushort4 o;
        o.x = f2bf(v.x); o.y = f2bf(v.y); o.z = f2bf(v.z); o.w = f2bf(v.w);
        out4[i] = o;
    }
}

// ---------------- persistent cooperative LSTM ----------------
// WG w owns h-columns [4w, 4w+4). Gate rows (global): gate*1024 + 4w + col, gate in {i,f,g,o}.
// Local j = gate*4 + col  (0..15).
// Wave v handles batch rows [16v, 16v+16).
__global__ void __launch_bounds__(256, 1) lstm_coop(
    const u16* Xbf,               // [SEQ][BATCH][HID] bf16
    u16* Y0bf,                    // [SEQ][BATCH][HID] bf16 (layer-0 outputs)
    u16* __restrict__ hbuf,       // [2][BATCH][HID] bf16 (double-buffered h)
    const float* __restrict__ h0, // [2][BATCH][HID]
    const float* __restrict__ c0, // [2][BATCH][HID]
    const float* __restrict__ Wx, // [2][4096][1024]
    const float* __restrict__ bx, // [2][4096]
    const float* __restrict__ Wh, // [2][4096][1024]
    const float* __restrict__ bh, // [2][4096]
    float* __restrict__ out)      // ys[SEQ][BATCH][HID] | hT[2][B][H] | cT[2][B][H]
{
    cg::grid_group grid = cg::this_grid();

    __shared__ u16   WxL[16 * LDK];
    __shared__ u16   WhL[16 * LDK];
    __shared__ float biasL[16];
    __shared__ float gbuf[4][16][17];   // [wave][batch-local][local j], padded

    const int wg   = blockIdx.x;
    const int hc0  = wg * 4;
    const int tid  = threadIdx.x;
    const int wv   = tid >> 6;          // wave 0..3
    const int lane = tid & 63;
    const int fr   = lane & 15;         // MFMA frag row (A) / col (B,D)
    const int fg   = lane >> 4;         // k-group 0..3
    const int bl   = lane >> 2;         // cell: batch-local 0..15
    const int col  = lane & 3;          // cell: h-column within WG slice
    const int b_cell = wv * 16 + bl;

    float* ys = out;
    float* hT = out + (size_t)SEQ * BATCH * HID;
    float* cT = hT + (size_t)2 * BATCH * HID;

    for (int layer = 0; layer < 2; ++layer) {
        // ---- stage weight slices (fp32 -> bf16) into LDS; rows j=gate*4+col
        for (int j = 0; j < 16; ++j) {
            int gate = j >> 2, jc = j & 3;
            size_t row = (size_t)layer * G4 + (size_t)gate * HID + hc0 + jc;
            const float4* sx = (const float4*)(Wx + row * HID);
            const float4* sh = (const float4*)(Wh + row * HID);
            float4 vx = sx[tid];
            float4 vh = sh[tid];
            ushort4 ox, oh;
            ox.x = f2bf(vx.x); ox.y = f2bf(vx.y); ox.z = f2bf(vx.z); ox.w = f2bf(vx.w);
            oh.x = f2bf(vh.x); oh.y = f2bf(vh.y); oh.z = f2bf(vh.z); oh.w = f2bf(vh.w);
            *(ushort4*)&WxL[j * LDK + tid * 4] = ox;
            *(ushort4*)&WhL[j * LDK + tid * 4] = oh;
        }
        if (tid < 16) {
            int gate = tid >> 2, jc = tid & 3;
            int row = layer * G4 + gate * HID + hc0 + jc;
            biasL[tid] = bx[row] + bh[row];
        }
        // ---- init h (own columns) and c (per-lane register)
        {
            int b = tid >> 2, cc = tid & 3;
            float hv = h0[(size_t)layer * BATCH * HID + (size_t)b * HID + hc0 + cc];
            hbuf[(size_t)b * HID + hc0 + cc] = f2bf(hv);   // buffer 0
        }
        float c_reg = c0[(size_t)layer * BATCH * HID + (size_t)b_cell * HID + hc0 + col];
        __syncthreads();
        grid.sync();

        const u16* Xsrc = (layer == 0) ? Xbf : Y0bf;
        int cur = 0;
        float h_out = 0.f;

        for (int t = 0; t < SEQ; ++t) {
            const u16* A0 = Xsrc + (size_t)t * BATCH * HID + (size_t)(wv * 16 + fr) * HID + fg * 8;
            const u16* A1 = hbuf + (size_t)cur * BATCH * HID + (size_t)(wv * 16 + fr) * HID + fg * 8;
            const u16* B0 = &WxL[fr * LDK + fg * 8];
            const u16* B1 = &WhL[fr * LDK + fg * 8];

            f32x4 acc = {0.f, 0.f, 0.f, 0.f};
            #pragma unroll 8
            for (int ks = 0; ks < 32; ++ks) {
                bf16x8 a = *(const bf16x8*)(A0 + ks * 32);
                bf16x8 b = *(const bf16x8*)(B0 + ks * 32);
                acc = __builtin_amdgcn_mfma_f32_16x16x32_bf16(a, b, acc, 0, 0, 0);
            }
            #pragma unroll 8
            for (int ks = 0; ks < 32; ++ks) {
                bf16x8 a = *(const bf16x8*)(A1 + ks * 32);
                bf16x8 b = *(const bf16x8*)(B1 + ks * 32);
                acc = __builtin_amdgcn_mfma_f32_16x16x32_bf16(a, b, acc, 0, 0, 0);
            }

            float bias = biasL[fr];
            // D layout: col=lane&15 (=local j), row=(lane>>4)*4+i (=batch-local)
            gbuf[wv][fg * 4 + 0][fr] = acc[0] + bias;
            gbuf[wv][fg * 4 + 1][fr] = acc[1] + bias;
            gbuf[wv][fg * 4 + 2][fr] = acc[2] + bias;
            gbuf[wv][fg * 4 + 3][fr] = acc[3] + bias;
            // wave-internal exchange (compiler inserts lgkmcnt waits)
            float gi = gbuf[wv][bl][0 + col];
            float gf = gbuf[wv][bl][4 + col];
            float gg = gbuf[wv][bl][8 + col];
            float go = gbuf[wv][bl][12 + col];

            c_reg = sigmoid_f(gf) * c_reg + sigmoid_f(gi) * tanh_f(gg);
            h_out = sigmoid_f(go) * tanh_f(c_reg);

            u16 hb = f2bf(h_out);
            hbuf[(size_t)(cur ^ 1) * BATCH * HID + (size_t)b_cell * HID + hc0 + col] = hb;
            if (layer == 0) {
                Y0bf[(size_t)t * BATCH * HID + (size_t)b_cell * HID + hc0 + col] = hb;
            } else {
                ys[(size_t)t * BATCH * HID + (size_t)b_cell * HID + hc0 + col] = h_out;
            }

            grid.sync();
            cur ^= 1;
        }

        hT[(size_t)layer * BATCH * HID + (size_t)b_cell * HID + hc0 + col] = h_out;
        cT[(size_t)layer * BATCH * HID + (size_t)b_cell * HID + hc0 + col] = c_reg;

        grid.sync();        // everyone done before LDS/hbuf reuse for next layer
        __syncthreads();
    }
}

extern "C" void kernel_launch(void* const* d_in, const int* in_sizes, int n_in,
                              void* d_out, int out_size, void* d_ws, size_t ws_size,
                              hipStream_t stream) {
    const float* x  = (const float*)d_in[0];
    const float* h0 = (const float*)d_in[1];
    const float* c0 = (const float*)d_in[2];
    const float* Wx = (const float*)d_in[3];
    const float* bx = (const float*)d_in[4];
    const float* Wh = (const float*)d_in[5];
    const float* bh = (const float*)d_in[6];
    float* out = (float*)d_out;

    u16* Xbf  = (u16*)d_ws;                                   // 16,777,216 elems
    u16* Y0bf = Xbf + (size_t)SEQ * BATCH * HID;              // 16,777,216 elems
    u16* hbuf = Y0bf + (size_t)SEQ * BATCH * HID;             // 2*65,536 elems

    int n4 = (SEQ * BATCH * HID) / 4;
    cvt_f32_bf16<<<dim3(1024), dim3(256), 0, stream>>>(x, Xbf, n4);

    void* args[] = {(void*)&Xbf, (void*)&Y0bf, (void*)&hbuf,
                    (void*)&h0, (void*)&c0, (void*)&Wx, (void*)&bx,
                    (void*)&Wh, (void*)&bh, (void*)&out};
    hipLaunchCooperativeKernel((void*)lstm_coop, dim3(NWG), dim3(256), args, 0, stream);
}

// Round 2
// 10897.611 us; speedup vs baseline: 1.8691x; 1.8691x over previous
//
#include <hip/hip_runtime.h>
#include <hip/hip_bf16.h>

#define SEQ    256
#define BATCH  64
#define HID    1024
#define G4     4096
#define NWG    256
#define LDK    1032   // padded LDS row stride (bf16 elems): 2064B rows, 2-way bank alias only

typedef __bf16 bf16x8 __attribute__((ext_vector_type(8)));
typedef float  f32x4  __attribute__((ext_vector_type(4)));
typedef unsigned short u16;

__device__ __forceinline__ u16 f2bf(float f) {
    unsigned int u = __float_as_uint(f);
    unsigned int r = (u + 0x7fffu + ((u >> 16) & 1u)) >> 16;  // RNE
    return (u16)r;
}

__device__ __forceinline__ float sigmoid_f(float x) {
    x = fminf(fmaxf(x, -30.f), 30.f);
    return 1.f / (1.f + __expf(-x));
}
__device__ __forceinline__ float tanh_f(float x) {
    x = fminf(fmaxf(x, -15.f), 15.f);
    float e2 = __expf(2.f * x);
    return (e2 - 1.f) / (e2 + 1.f);
}

// ---- custom grid barrier: monotonic target, agent-scope, light spin ----
// cnt and sense live in d_ws (zeroed by cvt kernel each launch).
__device__ __forceinline__ void grid_barrier(int* cnt, int* sense, int target) {
    __syncthreads();
    if (threadIdx.x == 0) {
        __threadfence();   // release: writeback my L2 so other XCDs see h/y stores
        int prev = __hip_atomic_fetch_add(cnt, 1, __ATOMIC_RELAXED, __HIP_MEMORY_SCOPE_AGENT);
        if (prev == NWG - 1) {
            __hip_atomic_store(cnt, 0, __ATOMIC_RELAXED, __HIP_MEMORY_SCOPE_AGENT);
            __hip_atomic_store(sense, target, __ATOMIC_RELEASE, __HIP_MEMORY_SCOPE_AGENT);
        } else {
            while (__hip_atomic_load(sense, __ATOMIC_RELAXED, __HIP_MEMORY_SCOPE_AGENT) < target)
                __builtin_amdgcn_s_sleep(1);
        }
        __threadfence();   // acquire: invalidate L1/L2 so plain loads see remote h
    }
    __syncthreads();
}

// ---------------- fp32 -> bf16 conversion (x) + barrier-state init ----------------
__global__ void cvt_f32_bf16(const float* __restrict__ in, u16* __restrict__ out, int n4,
                             int* __restrict__ barrier_state) {
    int idx = blockIdx.x * blockDim.x + threadIdx.x;
    if (idx == 0) { barrier_state[0] = 0; barrier_state[32] = 0; }
    int stride = gridDim.x * blockDim.x;
    const float4* in4 = (const float4*)in;
    ushort4* out4 = (ushort4*)out;
    for (int i = idx; i < n4; i += stride) {
        float4 v = in4[i];
        ushort4 o;
        o.x = f2bf(v.x); o.y = f2bf(v.y); o.z = f2bf(v.z); o.w = f2bf(v.w);
        out4[i] = o;
    }
}

// ---------------- persistent cooperative LSTM ----------------
// WG w owns h-columns [4w, 4w+4). Local gate row j = gate*4 + col (0..15).
// Wave v handles batch rows [16v, 16v+16).
__global__ void __launch_bounds__(256, 1) lstm_coop(
    const u16* Xbf,               // [SEQ][BATCH][HID] bf16
    u16* Y0bf,                    // [SEQ][BATCH][HID] bf16 (layer-0 outputs)
    u16* __restrict__ hbuf,       // [2][BATCH][HID] bf16 (double-buffered h)
    int* __restrict__ bar,        // barrier state: cnt at [0], sense at [32]
    const float* __restrict__ h0,
    const float* __restrict__ c0,
    const float* __restrict__ Wx, // [2][4096][1024]
    const float* __restrict__ bx,
    const float* __restrict__ Wh, // [2][4096][1024]
    const float* __restrict__ bh,
    float* __restrict__ out)      // ys | hT | cT
{
    __shared__ u16   WxL[16 * LDK];
    __shared__ u16   WhL[16 * LDK];
    __shared__ float biasL[16];
    __shared__ float gbuf[4][16][17];

    const int wg   = blockIdx.x;
    const int hc0  = wg * 4;
    const int tid  = threadIdx.x;
    const int wv   = tid >> 6;
    const int lane = tid & 63;
    const int fr   = lane & 15;
    const int fg   = lane >> 4;
    const int bl   = lane >> 2;
    const int col  = lane & 3;
    const int b_cell = wv * 16 + bl;

    int* cnt   = bar;
    int* sense = bar + 32;
    int bar_id = 0;

    float* ys = out;
    float* hT = out + (size_t)SEQ * BATCH * HID;
    float* cT = hT + (size_t)2 * BATCH * HID;

    for (int layer = 0; layer < 2; ++layer) {
        for (int j = 0; j < 16; ++j) {
            int gate = j >> 2, jc = j & 3;
            size_t row = (size_t)layer * G4 + (size_t)gate * HID + hc0 + jc;
            const float4* sx = (const float4*)(Wx + row * HID);
            const float4* sh = (const float4*)(Wh + row * HID);
            float4 vx = sx[tid];
            float4 vh = sh[tid];
            ushort4 ox, oh;
            ox.x = f2bf(vx.x); ox.y = f2bf(vx.y); ox.z = f2bf(vx.z); ox.w = f2bf(vx.w);
            oh.x = f2bf(vh.x); oh.y = f2bf(vh.y); oh.z = f2bf(vh.z); oh.w = f2bf(vh.w);
            *(ushort4*)&WxL[j * LDK + tid * 4] = ox;
            *(ushort4*)&WhL[j * LDK + tid * 4] = oh;
        }
        if (tid < 16) {
            int gate = tid >> 2, jc = tid & 3;
            int row = layer * G4 + gate * HID + hc0 + jc;
            biasL[tid] = bx[row] + bh[row];
        }
        {
            int b = tid >> 2, cc = tid & 3;
            float hv = h0[(size_t)layer * BATCH * HID + (size_t)b * HID + hc0 + cc];
            hbuf[(size_t)b * HID + hc0 + cc] = f2bf(hv);
        }
        float c_reg = c0[(size_t)layer * BATCH * HID + (size_t)b_cell * HID + hc0 + col];
        grid_barrier(cnt, sense, ++bar_id);

        const u16* Xsrc = (layer == 0) ? Xbf : Y0bf;
        int cur = 0;
        float h_out = 0.f;

        for (int t = 0; t < SEQ; ++t) {
            const u16* A0 = Xsrc + (size_t)t * BATCH * HID + (size_t)(wv * 16 + fr) * HID + fg * 8;
            const u16* A1 = hbuf + (size_t)cur * BATCH * HID + (size_t)(wv * 16 + fr) * HID + fg * 8;
            const u16* B0 = &WxL[fr * LDK + fg * 8];
            const u16* B1 = &WhL[fr * LDK + fg * 8];

            f32x4 acc = {0.f, 0.f, 0.f, 0.f};
            #pragma unroll 8
            for (int ks = 0; ks < 32; ++ks) {
                bf16x8 a = *(const bf16x8*)(A0 + ks * 32);
                bf16x8 b = *(const bf16x8*)(B0 + ks * 32);
                acc = __builtin_amdgcn_mfma_f32_16x16x32_bf16(a, b, acc, 0, 0, 0);
            }
            #pragma unroll 8
            for (int ks = 0; ks < 32; ++ks) {
                bf16x8 a = *(const bf16x8*)(A1 + ks * 32);
                bf16x8 b = *(const bf16x8*)(B1 + ks * 32);
                acc = __builtin_amdgcn_mfma_f32_16x16x32_bf16(a, b, acc, 0, 0, 0);
            }

            float bias = biasL[fr];
            gbuf[wv][fg * 4 + 0][fr] = acc[0] + bias;
            gbuf[wv][fg * 4 + 1][fr] = acc[1] + bias;
            gbuf[wv][fg * 4 + 2][fr] = acc[2] + bias;
            gbuf[wv][fg * 4 + 3][fr] = acc[3] + bias;
            float gi = gbuf[wv][bl][0 + col];
            float gf = gbuf[wv][bl][4 + col];
            float gg = gbuf[wv][bl][8 + col];
            float go = gbuf[wv][bl][12 + col];

            c_reg = sigmoid_f(gf) * c_reg + sigmoid_f(gi) * tanh_f(gg);
            h_out = sigmoid_f(go) * tanh_f(c_reg);

            u16 hb = f2bf(h_out);
            hbuf[(size_t)(cur ^ 1) * BATCH * HID + (size_t)b_cell * HID + hc0 + col] = hb;
            if (layer == 0) {
                Y0bf[(size_t)t * BATCH * HID + (size_t)b_cell * HID + hc0 + col] = hb;
            } else {
                ys[(size_t)t * BATCH * HID + (size_t)b_cell * HID + hc0 + col] = h_out;
            }

            grid_barrier(cnt, sense, ++bar_id);
            cur ^= 1;
        }

        hT[(size_t)layer * BATCH * HID + (size_t)b_cell * HID + hc0 + col] = h_out;
        cT[(size_t)layer * BATCH * HID + (size_t)b_cell * HID + hc0 + col] = c_reg;

        grid_barrier(cnt, sense, ++bar_id);
    }
}

extern "C" void kernel_launch(void* const* d_in, const int* in_sizes, int n_in,
                              void* d_out, int out_size, void* d_ws, size_t ws_size,
                              hipStream_t stream) {
    const float* x  = (const float*)d_in[0];
    const float* h0 = (const float*)d_in[1];
    const float* c0 = (const float*)d_in[2];
    const float* Wx = (const float*)d_in[3];
    const float* bx = (const float*)d_in[4];
    const float* Wh = (const float*)d_in[5];
    const float* bh = (const float*)d_in[6];
    float* out = (float*)d_out;

    u16* Xbf  = (u16*)d_ws;
    u16* Y0bf = Xbf + (size_t)SEQ * BATCH * HID;
    u16* hbuf = Y0bf + (size_t)SEQ * BATCH * HID;
    int* bar  = (int*)(hbuf + (size_t)2 * BATCH * HID);

    int n4 = (SEQ * BATCH * HID) / 4;
    cvt_f32_bf16<<<dim3(1024), dim3(256), 0, stream>>>(x, Xbf, n4, bar);

    void* args[] = {(void*)&Xbf, (void*)&Y0bf, (void*)&hbuf, (void*)&bar,
                    (void*)&h0, (void*)&c0, (void*)&Wx, (void*)&bx,
                    (void*)&Wh, (void*)&bh, (void*)&out};
    hipLaunchCooperativeKernel((void*)lstm_coop, dim3(NWG), dim3(256), args, 0, stream);
}

// Round 3
// 5738.231 us; speedup vs baseline: 3.5496x; 1.8991x over previous
//
#include <hip/hip_runtime.h>
#include <hip/hip_bf16.h>

#define SEQ    256
#define BATCH  64
#define HID    1024
#define G4     4096
#define NWG    256
#define LDK    1032   // padded LDS row stride (bf16 elems): 2064B rows, 2-way bank alias only

typedef __bf16 bf16x8 __attribute__((ext_vector_type(8)));
typedef float  f32x4  __attribute__((ext_vector_type(4)));
typedef unsigned short u16;

__device__ __forceinline__ u16 f2bf(float f) {
    unsigned int u = __float_as_uint(f);
    unsigned int r = (u + 0x7fffu + ((u >> 16) & 1u)) >> 16;  // RNE
    return (u16)r;
}

__device__ __forceinline__ float sigmoid_f(float x) {
    x = fminf(fmaxf(x, -30.f), 30.f);
    return 1.f / (1.f + __expf(-x));
}
__device__ __forceinline__ float tanh_f(float x) {
    x = fminf(fmaxf(x, -15.f), 15.f);
    float e2 = __expf(2.f * x);
    return (e2 - 1.f) / (e2 + 1.f);
}

// ---- fast grid barrier: 2-level monotonic tree, relaxed agent atomics, NO fences ----
// bar[64*g] g=0..7 : leaf counters (256B apart); bar[768]: root; bar[832]: sense.
// Monotonic: leaf-last when count hits 32*target; root-last at 8*target. No resets.
__device__ __forceinline__ void grid_barrier_fast(int* bar, int target) {
    // drain ALL outstanding vmem (incl. our inline-asm sc stores, which the
    // compiler's waitcnt model doesn't track) before signaling arrival.
    asm volatile("s_waitcnt vmcnt(0)" ::: "memory");
    __syncthreads();
    if (threadIdx.x == 0) {
        int* leaf  = bar + 64 * (blockIdx.x & 7);
        int* root  = bar + 768;
        int* sense = bar + 832;
        int p = __hip_atomic_fetch_add(leaf, 1, __ATOMIC_RELAXED, __HIP_MEMORY_SCOPE_AGENT);
        if (p == 32 * target - 1) {
            int q = __hip_atomic_fetch_add(root, 1, __ATOMIC_RELAXED, __HIP_MEMORY_SCOPE_AGENT);
            if (q == 8 * target - 1) {
                __hip_atomic_store(sense, target, __ATOMIC_RELAXED, __HIP_MEMORY_SCOPE_AGENT);
            } else {
                while (__hip_atomic_load(sense, __ATOMIC_RELAXED, __HIP_MEMORY_SCOPE_AGENT) < target)
                    __builtin_amdgcn_s_sleep(1);
            }
        } else {
            while (__hip_atomic_load(sense, __ATOMIC_RELAXED, __HIP_MEMORY_SCOPE_AGENT) < target)
                __builtin_amdgcn_s_sleep(1);
        }
    }
    __syncthreads();
}

// heavy barrier: full L2 writeback/invalidate around it (layer boundaries only)
__device__ __forceinline__ void grid_barrier_heavy(int* bar, int target) {
    if (threadIdx.x == 0) __threadfence();   // release: wbl2 my dirty Y0/hbuf-init lines
    grid_barrier_fast(bar, target);
    if (threadIdx.x == 0) __threadfence();   // acquire: inv stale L1/L2 copies
    __syncthreads();
}

// ---------------- fp32 -> bf16 conversion (x) + barrier-state init ----------------
__global__ void cvt_f32_bf16(const float* __restrict__ in, u16* __restrict__ out, int n4,
                             int* __restrict__ bar) {
    int idx = blockIdx.x * blockDim.x + threadIdx.x;
    if (idx < 1024) bar[idx] = 0;
    int stride = gridDim.x * blockDim.x;
    const float4* in4 = (const float4*)in;
    ushort4* out4 = (ushort4*)out;
    for (int i = idx; i < n4; i += stride) {
        float4 v = in4[i];
        ushort4 o;
        o.x = f2bf(v.x); o.y = f2bf(v.y); o.z = f2bf(v.z); o.w = f2bf(v.w);
        out4[i] = o;
    }
}

// issue one coherent (L2-bypassing) 16B h-frag load at byte offset OFFS
#define LDH(k, OFFS) \
    asm volatile("global_load_dwordx4 %0, %1, off offset:" OFFS " sc0 sc1" \
                 : "=v"(hf[k]) : "v"(A1))

// ---------------- persistent cooperative LSTM ----------------
__global__ void __launch_bounds__(256, 1) lstm_coop(
    const u16* Xbf,               // [SEQ][BATCH][HID] bf16
    u16* Y0bf,                    // [SEQ][BATCH][HID] bf16 (layer-0 outputs)
    u16* __restrict__ hbuf,       // [2][BATCH][HID] bf16 (double-buffered h)
    int* __restrict__ bar,        // barrier state
    const float* __restrict__ h0,
    const float* __restrict__ c0,
    const float* __restrict__ Wx, // [2][4096][1024]
    const float* __restrict__ bx,
    const float* __restrict__ Wh, // [2][4096][1024]
    const float* __restrict__ bh,
    float* __restrict__ out)      // ys | hT | cT
{
    __shared__ u16   WxL[16 * LDK];
    __shared__ u16   WhL[16 * LDK];
    __shared__ float biasL[16];
    __shared__ float gbuf[4][16][17];

    const int wg   = blockIdx.x;
    const int hc0  = wg * 4;
    const int tid  = threadIdx.x;
    const int wv   = tid >> 6;
    const int lane = tid & 63;
    const int fr   = lane & 15;
    const int fg   = lane >> 4;
    const int bl   = lane >> 2;
    const int col  = lane & 3;
    const int b_cell = wv * 16 + bl;

    int bar_id = 0;

    float* ys = out;
    float* hT = out + (size_t)SEQ * BATCH * HID;
    float* cT = hT + (size_t)2 * BATCH * HID;

    for (int layer = 0; layer < 2; ++layer) {
        for (int j = 0; j < 16; ++j) {
            int gate = j >> 2, jc = j & 3;
            size_t row = (size_t)layer * G4 + (size_t)gate * HID + hc0 + jc;
            const float4* sx = (const float4*)(Wx + row * HID);
            const float4* sh = (const float4*)(Wh + row * HID);
            float4 vx = sx[tid];
            float4 vh = sh[tid];
            ushort4 ox, oh;
            ox.x = f2bf(vx.x); ox.y = f2bf(vx.y); ox.z = f2bf(vx.z); ox.w = f2bf(vx.w);
            oh.x = f2bf(vh.x); oh.y = f2bf(vh.y); oh.z = f2bf(vh.z); oh.w = f2bf(vh.w);
            *(ushort4*)&WxL[j * LDK + tid * 4] = ox;
            *(ushort4*)&WhL[j * LDK + tid * 4] = oh;
        }
        if (tid < 16) {
            int gate = tid >> 2, jc = tid & 3;
            int row = layer * G4 + gate * HID + hc0 + jc;
            biasL[tid] = bx[row] + bh[row];
        }
        {
            int b = tid >> 2, cc = tid & 3;
            float hv = h0[(size_t)layer * BATCH * HID + (size_t)b * HID + hc0 + cc];
            hbuf[(size_t)b * HID + hc0 + cc] = f2bf(hv);   // buffer 0 (plain; flushed below)
        }
        float c_reg = c0[(size_t)layer * BATCH * HID + (size_t)b_cell * HID + hc0 + col];
        grid_barrier_heavy(bar, ++bar_id);   // publish hbuf init (+ Y0 from prev layer)

        const u16* Xsrc = (layer == 0) ? Xbf : Y0bf;
        int cur = 0;
        float h_out = 0.f;

        for (int t = 0; t < SEQ; ++t) {
            const u16* A0 = Xsrc + (size_t)t * BATCH * HID + (size_t)(wv * 16 + fr) * HID + fg * 8;
            const u16* A1 = hbuf + (size_t)cur * BATCH * HID + (size_t)(wv * 16 + fr) * HID + fg * 8;
            const u16* B0 = &WxL[fr * LDK + fg * 8];
            const u16* B1 = &WhL[fr * LDK + fg * 8];

            f32x4 acc = {0.f, 0.f, 0.f, 0.f};

            // ---- x GEMM (cached loads; x stays hot in L2 now) ----
            #pragma unroll 8
            for (int ks = 0; ks < 32; ++ks) {
                bf16x8 a = *(const bf16x8*)(A0 + ks * 32);
                bf16x8 b = *(const bf16x8*)(B0 + ks * 32);
                acc = __builtin_amdgcn_mfma_f32_16x16x32_bf16(a, b, acc, 0, 0, 0);
            }

            // ---- h GEMM: issue all 32 coherent loads, one wait, then MFMAs ----
            bf16x8 hf[32];
            LDH( 0,    "0"); LDH( 1,   "64"); LDH( 2,  "128"); LDH( 3,  "192");
            LDH( 4,  "256"); LDH( 5,  "320"); LDH( 6,  "384"); LDH( 7,  "448");
            LDH( 8,  "512"); LDH( 9,  "576"); LDH(10,  "640"); LDH(11,  "704");
            LDH(12,  "768"); LDH(13,  "832"); LDH(14,  "896"); LDH(15,  "960");
            LDH(16, "1024"); LDH(17, "1088"); LDH(18, "1152"); LDH(19, "1216");
            LDH(20, "1280"); LDH(21, "1344"); LDH(22, "1408"); LDH(23, "1472");
            LDH(24, "1536"); LDH(25, "1600"); LDH(26, "1664"); LDH(27, "1728");
            LDH(28, "1792"); LDH(29, "1856"); LDH(30, "1920"); LDH(31, "1984");
            asm volatile("s_waitcnt vmcnt(0)" ::: "memory");
            __builtin_amdgcn_sched_barrier(0);
            #pragma unroll
            for (int ks = 0; ks < 32; ++ks) {
                bf16x8 b = *(const bf16x8*)(B1 + ks * 32);
                acc = __builtin_amdgcn_mfma_f32_16x16x32_bf16(hf[ks], b, acc, 0, 0, 0);
            }

            float bias = biasL[fr];
            gbuf[wv][fg * 4 + 0][fr] = acc[0] + bias;
            gbuf[wv][fg * 4 + 1][fr] = acc[1] + bias;
            gbuf[wv][fg * 4 + 2][fr] = acc[2] + bias;
            gbuf[wv][fg * 4 + 3][fr] = acc[3] + bias;
            float gi = gbuf[wv][bl][0 + col];
            float gf = gbuf[wv][bl][4 + col];
            float gg = gbuf[wv][bl][8 + col];
            float go = gbuf[wv][bl][12 + col];

            c_reg = sigmoid_f(gf) * c_reg + sigmoid_f(gi) * tanh_f(gg);
            h_out = sigmoid_f(go) * tanh_f(c_reg);

            u16 hb = f2bf(h_out);
            // coherent write-through h store (visible at L3 to all XCDs)
            {
                u16* hdst = hbuf + (size_t)(cur ^ 1) * BATCH * HID + (size_t)b_cell * HID + hc0 + col;
                unsigned int hv32 = hb;
                asm volatile("global_store_short %0, %1, off sc0 sc1"
                             :: "v"(hdst), "v"(hv32) : "memory");
            }
            if (layer == 0) {
                Y0bf[(size_t)t * BATCH * HID + (size_t)b_cell * HID + hc0 + col] = hb;
            } else {
                ys[(size_t)t * BATCH * HID + (size_t)b_cell * HID + hc0 + col] = h_out;
            }

            grid_barrier_fast(bar, ++bar_id);
            cur ^= 1;
        }

        hT[(size_t)layer * BATCH * HID + (size_t)b_cell * HID + hc0 + col] = h_out;
        cT[(size_t)layer * BATCH * HID + (size_t)b_cell * HID + hc0 + col] = c_reg;

        grid_barrier_heavy(bar, ++bar_id);   // publish Y0 before next layer reads it
    }
}

extern "C" void kernel_launch(void* const* d_in, const int* in_sizes, int n_in,
                              void* d_out, int out_size, void* d_ws, size_t ws_size,
                              hipStream_t stream) {
    const float* x  = (const float*)d_in[0];
    const float* h0 = (const float*)d_in[1];
    const float* c0 = (const float*)d_in[2];
    const float* Wx = (const float*)d_in[3];
    const float* bx = (const float*)d_in[4];
    const float* Wh = (const float*)d_in[5];
    const float* bh = (const float*)d_in[6];
    float* out = (float*)d_out;

    u16* Xbf  = (u16*)d_ws;
    u16* Y0bf = Xbf + (size_t)SEQ * BATCH * HID;
    u16* hbuf = Y0bf + (size_t)SEQ * BATCH * HID;
    int* bar  = (int*)(hbuf + (size_t)2 * BATCH * HID);

    int n4 = (SEQ * BATCH * HID) / 4;
    cvt_f32_bf16<<<dim3(1024), dim3(256), 0, stream>>>(x, Xbf, n4, bar);

    void* args[] = {(void*)&Xbf, (void*)&Y0bf, (void*)&hbuf, (void*)&bar,
                    (void*)&h0, (void*)&c0, (void*)&Wx, (void*)&bx,
                    (void*)&Wh, (void*)&bh, (void*)&out};
    hipLaunchCooperativeKernel((void*)lstm_coop, dim3(NWG), dim3(256), args, 0, stream);
}

// Round 4
// 4992.508 us; speedup vs baseline: 4.0798x; 1.1494x over previous
//
#include <hip/hip_runtime.h>
#include <hip/hip_bf16.h>

#define SEQ    256
#define BATCH  64
#define HID    1024
#define G4     4096
#define NWG    256
#define LDK    1032   // padded LDS row stride (bf16 elems): 2064B rows, 2-way bank alias only

typedef __bf16 bf16x8 __attribute__((ext_vector_type(8)));
typedef float  f32x4  __attribute__((ext_vector_type(4)));
typedef unsigned short u16;

__device__ __forceinline__ u16 f2bf(float f) {
    unsigned int u = __float_as_uint(f);
    unsigned int r = (u + 0x7fffu + ((u >> 16) & 1u)) >> 16;  // RNE
    return (u16)r;
}

__device__ __forceinline__ float sigmoid_f(float x) {
    x = fminf(fmaxf(x, -30.f), 30.f);
    return 1.f / (1.f + __expf(-x));
}
__device__ __forceinline__ float tanh_f(float x) {
    x = fminf(fmaxf(x, -15.f), 15.f);
    float e2 = __expf(2.f * x);
    return (e2 - 1.f) / (e2 + 1.f);
}

// ---- split grid barrier: 2-level monotonic tree, relaxed agent atomics ----
// bar[64*g] g=0..7 : leaf counters; bar[768]: root; bar[832]: sense. Monotonic, no resets.
__device__ __forceinline__ void bar_arrive(int* bar, int target) {
    // each wave drains its own outstanding vmem (incl. inline-asm sc stores)
    asm volatile("s_waitcnt vmcnt(0)" ::: "memory");
    __syncthreads();   // all waves of this WG drained
    if (threadIdx.x == 0) {
        int* leaf  = bar + 64 * (blockIdx.x & 7);
        int* root  = bar + 768;
        int* sense = bar + 832;
        int p = __hip_atomic_fetch_add(leaf, 1, __ATOMIC_RELAXED, __HIP_MEMORY_SCOPE_AGENT);
        if (p == 32 * target - 1) {
            int q = __hip_atomic_fetch_add(root, 1, __ATOMIC_RELAXED, __HIP_MEMORY_SCOPE_AGENT);
            if (q == 8 * target - 1)
                __hip_atomic_store(sense, target, __ATOMIC_RELAXED, __HIP_MEMORY_SCOPE_AGENT);
        }
    }
}

__device__ __forceinline__ void bar_wait(int* bar, int target) {
    if (threadIdx.x == 0) {
        int* sense = bar + 832;
        while (__hip_atomic_load(sense, __ATOMIC_RELAXED, __HIP_MEMORY_SCOPE_AGENT) < target)
            __builtin_amdgcn_s_sleep(1);
    }
    __syncthreads();
}

// heavy barrier: full L2 writeback/invalidate around it (layer boundaries only)
__device__ __forceinline__ void bar_heavy(int* bar, int target) {
    if (threadIdx.x == 0) __threadfence();   // release: wbl2 dirty Y0/hbuf-init lines
    bar_arrive(bar, target);
    bar_wait(bar, target);
    if (threadIdx.x == 0) __threadfence();   // acquire: inv stale L1/L2 copies
    __syncthreads();
}

// ---------------- fp32 -> bf16 conversion (x) + barrier-state init ----------------
__global__ void cvt_f32_bf16(const float* __restrict__ in, u16* __restrict__ out, int n4,
                             int* __restrict__ bar) {
    int idx = blockIdx.x * blockDim.x + threadIdx.x;
    if (idx < 1024) bar[idx] = 0;
    int stride = gridDim.x * blockDim.x;
    const float4* in4 = (const float4*)in;
    ushort4* out4 = (ushort4*)out;
    for (int i = idx; i < n4; i += stride) {
        float4 v = in4[i];
        ushort4 o;
        o.x = f2bf(v.x); o.y = f2bf(v.y); o.z = f2bf(v.z); o.w = f2bf(v.w);
        out4[i] = o;
    }
}

// x-GEMM for one step: A from global (L2-cached), B from LDS. 32 MFMAs.
__device__ __forceinline__ f32x4 xgemm(const u16* __restrict__ A0, const u16* B0) {
    f32x4 acc = {0.f, 0.f, 0.f, 0.f};
    #pragma unroll 8
    for (int ks = 0; ks < 32; ++ks) {
        bf16x8 a = *(const bf16x8*)(A0 + ks * 32);
        bf16x8 b = *(const bf16x8*)(B0 + ks * 32);
        acc = __builtin_amdgcn_mfma_f32_16x16x32_bf16(a, b, acc, 0, 0, 0);
    }
    return acc;
}

// issue one coherent (L2-bypassing) 16B h-frag load at byte offset OFFS
#define LDH(k, OFFS) \
    asm volatile("global_load_dwordx4 %0, %1, off offset:" OFFS " sc0 sc1" \
                 : "=v"(hf[k]) : "v"(A1))

// ---------------- persistent cooperative LSTM ----------------
__global__ void __launch_bounds__(256, 1) lstm_coop(
    const u16* Xbf,               // [SEQ][BATCH][HID] bf16
    u16* Y0bf,                    // [SEQ][BATCH][HID] bf16 (layer-0 outputs)
    u16* __restrict__ hbuf,       // [2][BATCH][HID] bf16 (double-buffered h)
    int* __restrict__ bar,        // barrier state
    const float* __restrict__ h0,
    const float* __restrict__ c0,
    const float* __restrict__ Wx, // [2][4096][1024]
    const float* __restrict__ bx,
    const float* __restrict__ Wh, // [2][4096][1024]
    const float* __restrict__ bh,
    float* __restrict__ out)      // ys | hT | cT
{
    __shared__ u16   WxL[16 * LDK];
    __shared__ u16   WhL[16 * LDK];
    __shared__ float biasL[16];
    __shared__ float gbuf[4][16][17];

    const int wg   = blockIdx.x;
    const int hc0  = wg * 4;
    const int tid  = threadIdx.x;
    const int wv   = tid >> 6;
    const int lane = tid & 63;
    const int fr   = lane & 15;
    const int fg   = lane >> 4;
    const int bl   = lane >> 2;
    const int col  = lane & 3;
    const int b_cell = wv * 16 + bl;

    int bar_id = 0;

    float* ys = out;
    float* hT = out + (size_t)SEQ * BATCH * HID;
    float* cT = hT + (size_t)2 * BATCH * HID;

    for (int layer = 0; layer < 2; ++layer) {
        for (int j = 0; j < 16; ++j) {
            int gate = j >> 2, jc = j & 3;
            size_t row = (size_t)layer * G4 + (size_t)gate * HID + hc0 + jc;
            const float4* sx = (const float4*)(Wx + row * HID);
            const float4* sh = (const float4*)(Wh + row * HID);
            float4 vx = sx[tid];
            float4 vh = sh[tid];
            ushort4 ox, oh;
            ox.x = f2bf(vx.x); ox.y = f2bf(vx.y); ox.z = f2bf(vx.z); ox.w = f2bf(vx.w);
            oh.x = f2bf(vh.x); oh.y = f2bf(vh.y); oh.z = f2bf(vh.z); oh.w = f2bf(vh.w);
            *(ushort4*)&WxL[j * LDK + tid * 4] = ox;
            *(ushort4*)&WhL[j * LDK + tid * 4] = oh;
        }
        if (tid < 16) {
            int gate = tid >> 2, jc = tid & 3;
            int row = layer * G4 + gate * HID + hc0 + jc;
            biasL[tid] = bx[row] + bh[row];
        }
        {
            int b = tid >> 2, cc = tid & 3;
            float hv = h0[(size_t)layer * BATCH * HID + (size_t)b * HID + hc0 + cc];
            hbuf[(size_t)b * HID + hc0 + cc] = f2bf(hv);   // buffer 0 (published by heavy bar)
        }
        float c_reg = c0[(size_t)layer * BATCH * HID + (size_t)b_cell * HID + hc0 + col];
        bar_heavy(bar, ++bar_id);   // publish hbuf init (+ Y0 from prev layer)

        const u16* Xsrc = (layer == 0) ? Xbf : Y0bf;
        const u16* B0 = &WxL[fr * LDK + fg * 8];
        const u16* B1 = &WhL[fr * LDK + fg * 8];
        const size_t arow = (size_t)(wv * 16 + fr) * HID + fg * 8;
        int cur = 0;
        float h_out = 0.f;

        // prologue: x-GEMM for t=0
        f32x4 acc = xgemm(Xsrc + arow, B0);

        for (int t = 0; t < SEQ; ++t) {
            // ---- h GEMM: issue all 32 coherent loads, one wait, then MFMAs ----
            const u16* A1 = hbuf + (size_t)cur * BATCH * HID + arow;
            bf16x8 hf[32];
            LDH( 0,    "0"); LDH( 1,   "64"); LDH( 2,  "128"); LDH( 3,  "192");
            LDH( 4,  "256"); LDH( 5,  "320"); LDH( 6,  "384"); LDH( 7,  "448");
            LDH( 8,  "512"); LDH( 9,  "576"); LDH(10,  "640"); LDH(11,  "704");
            LDH(12,  "768"); LDH(13,  "832"); LDH(14,  "896"); LDH(15,  "960");
            LDH(16, "1024"); LDH(17, "1088"); LDH(18, "1152"); LDH(19, "1216");
            LDH(20, "1280"); LDH(21, "1344"); LDH(22, "1408"); LDH(23, "1472");
            LDH(24, "1536"); LDH(25, "1600"); LDH(26, "1664"); LDH(27, "1728");
            LDH(28, "1792"); LDH(29, "1856"); LDH(30, "1920"); LDH(31, "1984");
            asm volatile("s_waitcnt vmcnt(0)" ::: "memory");
            __builtin_amdgcn_sched_barrier(0);
            #pragma unroll
            for (int ks = 0; ks < 32; ++ks) {
                bf16x8 b = *(const bf16x8*)(B1 + ks * 32);
                acc = __builtin_amdgcn_mfma_f32_16x16x32_bf16(hf[ks], b, acc, 0, 0, 0);
            }

            float bias = biasL[fr];
            gbuf[wv][fg * 4 + 0][fr] = acc[0] + bias;
            gbuf[wv][fg * 4 + 1][fr] = acc[1] + bias;
            gbuf[wv][fg * 4 + 2][fr] = acc[2] + bias;
            gbuf[wv][fg * 4 + 3][fr] = acc[3] + bias;
            float gi = gbuf[wv][bl][0 + col];
            float gf = gbuf[wv][bl][4 + col];
            float gg = gbuf[wv][bl][8 + col];
            float go = gbuf[wv][bl][12 + col];

            c_reg = sigmoid_f(gf) * c_reg + sigmoid_f(gi) * tanh_f(gg);
            h_out = sigmoid_f(go) * tanh_f(c_reg);

            u16 hb = f2bf(h_out);
            {   // coherent write-through h store (visible at L3 to all XCDs)
                u16* hdst = hbuf + (size_t)(cur ^ 1) * BATCH * HID + (size_t)b_cell * HID + hc0 + col;
                unsigned int hv32 = hb;
                asm volatile("global_store_short %0, %1, off sc0 sc1"
                             :: "v"(hdst), "v"(hv32) : "memory");
            }
            if (layer == 0) {
                Y0bf[(size_t)t * BATCH * HID + (size_t)b_cell * HID + hc0 + col] = hb;
            } else {
                ys[(size_t)t * BATCH * HID + (size_t)b_cell * HID + hc0 + col] = h_out;
            }

            // ---- pipelined barrier: arrive, prefetch next x-GEMM, then wait ----
            int tgt = ++bar_id;
            bar_arrive(bar, tgt);
            int tn = (t + 1) & 255;
            f32x4 acc2 = xgemm(Xsrc + (size_t)tn * BATCH * HID + arow, B0);
            bar_wait(bar, tgt);
            acc = acc2;
            cur ^= 1;
        }

        hT[(size_t)layer * BATCH * HID + (size_t)b_cell * HID + hc0 + col] = h_out;
        cT[(size_t)layer * BATCH * HID + (size_t)b_cell * HID + hc0 + col] = c_reg;

        bar_heavy(bar, ++bar_id);   // publish Y0 before next layer reads it
    }
}

extern "C" void kernel_launch(void* const* d_in, const int* in_sizes, int n_in,
                              void* d_out, int out_size, void* d_ws, size_t ws_size,
                              hipStream_t stream) {
    const float* x  = (const float*)d_in[0];
    const float* h0 = (const float*)d_in[1];
    const float* c0 = (const float*)d_in[2];
    const float* Wx = (const float*)d_in[3];
    const float* bx = (const float*)d_in[4];
    const float* Wh = (const float*)d_in[5];
    const float* bh = (const float*)d_in[6];
    float* out = (float*)d_out;

    u16* Xbf  = (u16*)d_ws;
    u16* Y0bf = Xbf + (size_t)SEQ * BATCH * HID;
    u16* hbuf = Y0bf + (size_t)SEQ * BATCH * HID;
    int* bar  = (int*)(hbuf + (size_t)2 * BATCH * HID);

    int n4 = (SEQ * BATCH * HID) / 4;
    cvt_f32_bf16<<<dim3(1024), dim3(256), 0, stream>>>(x, Xbf, n4, bar);

    void* args[] = {(void*)&Xbf, (void*)&Y0bf, (void*)&hbuf, (void*)&bar,
                    (void*)&h0, (void*)&c0, (void*)&Wx, (void*)&bx,
                    (void*)&Wh, (void*)&bh, (void*)&out};
    hipLaunchCooperativeKernel((void*)lstm_coop, dim3(NWG), dim3(256), args, 0, stream);
}